// Round 3
// baseline (907.327 us; speedup 1.0000x reference)
//
#include <hip/hip_runtime.h>
#include <cfloat>
#include <cmath>

#define NROWS 16384
#define DDIM  4096
#define NEXP  64
#define TOPK  8
#define GAP_THRESH 5e-4f   // rows with any top-9 gap below this get fp64 rescue

// ---------------------------------------------------------------------------
// ws layout: [Wt4: 1MB][Wd: 2MB][count: 256B pad][list: 64KB]
// ---------------------------------------------------------------------------

// Kernel 1: prep. Wt4[kg*64+e] = W[e][4kg..4kg+3]; Wd = (double)W; count = 0.
__global__ __launch_bounds__(256) void prep_kernel(const float* __restrict__ W,
                                                   float4* __restrict__ Wt4,
                                                   double* __restrict__ Wd,
                                                   int* __restrict__ count) {
    int t = blockIdx.x * 256 + threadIdx.x;          // 0..262143
    Wd[t] = (double)W[t];
    if (t < NEXP * (DDIM / 4)) {                      // 65536 float4 entries
        int e  = t & 63;
        int kg = t >> 6;
        Wt4[t] = reinterpret_cast<const float4*>(W + (size_t)e * DDIM)[kg];
    }
    if (t == 0) *count = 0;
}

// ---------------------------------------------------------------------------
// Kernel 2: fp32 gate GEMM + top-9 + sparse softmax + ambiguity flagging.
// lane = expert; 8 rows per wave; x at wave-uniform addresses; Wt4 coalesced.
// ---------------------------------------------------------------------------
__global__ __launch_bounds__(256) void gate_kernel(
    const float*  __restrict__ x,
    const float4* __restrict__ Wt4,
    const float*  __restrict__ b,
    float* __restrict__ outp,    // [N, 64]
    float* __restrict__ outi,    // [N, 8]
    int*   __restrict__ count,
    int*   __restrict__ list)
{
    const int lane = threadIdx.x & 63;
    const int wid  = __builtin_amdgcn_readfirstlane((int)(threadIdx.x >> 6));
    const int nr0  = (blockIdx.x * 4 + wid) * 8;

    const float bv = b[lane];

    float acc[8];
#pragma unroll
    for (int r = 0; r < 8; ++r) acc[r] = 0.0f;

    const float4* xr[8];
#pragma unroll
    for (int r = 0; r < 8; ++r)
        xr[r] = reinterpret_cast<const float4*>(x + (size_t)(nr0 + r) * DDIM);

    for (int kg0 = 0; kg0 < DDIM / 4; kg0 += 8) {
        float4 w[8];
#pragma unroll
        for (int j = 0; j < 8; ++j)
            w[j] = Wt4[(size_t)(kg0 + j) * NEXP + lane];       // coalesced
#pragma unroll
        for (int r = 0; r < 8; ++r) {
            float a = acc[r];
#pragma unroll
            for (int j = 0; j < 8; ++j) {
                float4 xv = xr[r][kg0 + j];                    // wave-uniform
                a = fmaf(xv.x, w[j].x, a);
                a = fmaf(xv.y, w[j].y, a);
                a = fmaf(xv.z, w[j].z, a);
                a = fmaf(xv.w, w[j].w, a);
            }
            acc[r] = a;
        }
    }

    // ---- epilogue ---------------------------------------------------------
#pragma unroll
    for (int r = 0; r < 8; ++r) {
        const int n = nr0 + r;
        const float orig = acc[r] + bv;
        float cur = orig;

        float vals[9];
        float myidxf = 0.0f;
        bool  sel = false;

#pragma unroll
        for (int i = 0; i < 9; ++i) {
            float m = cur;
#pragma unroll
            for (int off = 32; off > 0; off >>= 1)
                m = fmaxf(m, __shfl_xor(m, off, 64));
            unsigned long long msk = __ballot(cur == m);
            int il = __ffsll((long long)msk) - 1;
            vals[i] = m;
            if (lane == il) { cur = -FLT_MAX; if (i < TOPK) sel = true; }
            if (i < TOPK && lane == i) myidxf = (float)il;
        }

        float ssum = 0.0f;
#pragma unroll
        for (int i = 0; i < TOPK; ++i) ssum += expf(vals[i] - vals[0]);
        float p = sel ? (expf(orig - vals[0]) / ssum) : 0.0f;

        outp[(size_t)n * NEXP + lane] = p;
        if (lane < TOPK) outi[(size_t)n * TOPK + lane] = myidxf;

        // ambiguity check: min gap among the 9 order statistics
        float mingap = FLT_MAX;
#pragma unroll
        for (int i = 0; i < 8; ++i) mingap = fminf(mingap, vals[i] - vals[i + 1]);
        if (lane == 0 && mingap < GAP_THRESH) {
            int pos = atomicAdd(count, 1);
            if (pos < NROWS) list[pos] = n;
        }
    }
}

// ---------------------------------------------------------------------------
// Kernel 3: fp64 rescue for flagged rows. One wave per row, grid-stride.
// lane = expert; full-K fp64 dot (Wd is L2-resident); fp64 top-8 + softmax.
// ---------------------------------------------------------------------------
__global__ __launch_bounds__(64) void fix_kernel(
    const float*  __restrict__ x,
    const double* __restrict__ Wd,
    const float*  __restrict__ b,
    float* __restrict__ outp,
    float* __restrict__ outi,
    const int* __restrict__ count,
    const int* __restrict__ list)
{
    const int lane = threadIdx.x;
    const int cnt  = *count;

    for (int i = blockIdx.x; i < cnt; i += gridDim.x) {
        const int row = list[i];
        const float*  xr = x  + (size_t)row  * DDIM;
        const double* wp = Wd + (size_t)lane * DDIM;

        double a0 = 0.0, a1 = 0.0, a2 = 0.0, a3 = 0.0;
        for (int k = 0; k < DDIM; k += 4) {
            a0 = fma((double)xr[k + 0], wp[k + 0], a0);
            a1 = fma((double)xr[k + 1], wp[k + 1], a1);
            a2 = fma((double)xr[k + 2], wp[k + 2], a2);
            a3 = fma((double)xr[k + 3], wp[k + 3], a3);
        }
        const double orig = ((a0 + a1) + (a2 + a3)) + (double)b[lane];
        double cur = orig;

        double vals[TOPK];
        float  myidxf = 0.0f;
        bool   sel = false;

#pragma unroll
        for (int t = 0; t < TOPK; ++t) {
            double m = cur;
#pragma unroll
            for (int off = 32; off > 0; off >>= 1) {
                double o = __shfl_xor(m, off, 64);
                m = fmax(m, o);
            }
            unsigned long long msk = __ballot(cur == m);
            int il = __ffsll((long long)msk) - 1;
            vals[t] = m;
            if (lane == il) { cur = -DBL_MAX; sel = true; }
            if (lane == t)   myidxf = (float)il;
        }

        double ssum = 0.0;
#pragma unroll
        for (int t = 0; t < TOPK; ++t) ssum += exp(vals[t] - vals[0]);
        float p = sel ? (float)(exp(orig - vals[0]) / ssum) : 0.0f;

        outp[(size_t)row * NEXP + lane] = p;
        if (lane < TOPK) outi[(size_t)row * TOPK + lane] = myidxf;
    }
}

// ---------------------------------------------------------------------------
// Fallback (tiny ws): per-thread-row full fp64 from f32 W. Slow but correct.
// ---------------------------------------------------------------------------
__global__ __launch_bounds__(64) void fallback_kernel(
    const float* __restrict__ x,
    const float* __restrict__ W,
    const float* __restrict__ b,
    float* __restrict__ outp,
    float* __restrict__ outi)
{
    const int row = blockIdx.x * 64 + threadIdx.x;
    double lg[64];
#pragma unroll
    for (int e = 0; e < 64; ++e) lg[e] = (double)b[e];
    const float* xr = x + (size_t)row * DDIM;
    for (int k = 0; k < DDIM; k += 4) {
        float4 xa = *reinterpret_cast<const float4*>(xr + k);
        double xd[4] = {(double)xa.x, (double)xa.y, (double)xa.z, (double)xa.w};
#pragma unroll
        for (int e = 0; e < 64; ++e) {
            const float* wp = W + (size_t)e * DDIM + k;
            double a = lg[e];
#pragma unroll
            for (int j = 0; j < 4; ++j) a = fma(xd[j], (double)wp[j], a);
            lg[e] = a;
        }
    }
    unsigned long long selm = 0ull;
    double vals[TOPK]; int idx[TOPK];
#pragma unroll
    for (int i = 0; i < TOPK; ++i) {
        double m = -DBL_MAX; int mi = 0;
#pragma unroll
        for (int e = 0; e < 64; ++e) {
            bool gt = !((selm >> e) & 1ull) && (lg[e] > m);
            m = gt ? lg[e] : m; mi = gt ? e : mi;
        }
        vals[i] = m; idx[i] = mi; selm |= (1ull << mi);
    }
    double ssum = 0.0;
#pragma unroll
    for (int i = 0; i < TOPK; ++i) ssum += exp(vals[i] - vals[0]);
    double inv = 1.0 / ssum;
#pragma unroll
    for (int e = 0; e < 64; ++e)
        outp[(size_t)row * NEXP + e] =
            ((selm >> e) & 1ull) ? (float)(exp(lg[e] - vals[0]) * inv) : 0.0f;
#pragma unroll
    for (int i = 0; i < TOPK; ++i)
        outi[(size_t)row * TOPK + i] = (float)idx[i];
}

// ---------------------------------------------------------------------------
extern "C" void kernel_launch(void* const* d_in, const int* in_sizes, int n_in,
                              void* d_out, int out_size, void* d_ws, size_t ws_size,
                              hipStream_t stream) {
    (void)in_sizes; (void)n_in; (void)out_size;
    const float* x = (const float*)d_in[0];
    const float* W = (const float*)d_in[1];
    const float* b = (const float*)d_in[2];

    float* outp = (float*)d_out;
    float* outi = outp + (size_t)NROWS * NEXP;

    const size_t wt4_bytes = sizeof(float4) * (size_t)(DDIM / 4) * NEXP;  // 1 MB
    const size_t wd_bytes  = sizeof(double) * (size_t)NEXP * DDIM;        // 2 MB
    const size_t cnt_off   = wt4_bytes + wd_bytes;
    const size_t list_off  = cnt_off + 256;
    const size_t need      = list_off + (size_t)NROWS * sizeof(int);

    if (ws_size >= need) {
        float4* Wt4  = (float4*)d_ws;
        double* Wd   = (double*)((char*)d_ws + wt4_bytes);
        int*    cnt  = (int*)((char*)d_ws + cnt_off);
        int*    list = (int*)((char*)d_ws + list_off);

        prep_kernel<<<(NEXP * DDIM) / 256, 256, 0, stream>>>(W, Wt4, Wd, cnt);
        gate_kernel<<<NROWS / 32, 256, 0, stream>>>(x, Wt4, b, outp, outi, cnt, list);
        fix_kernel<<<1024, 64, 0, stream>>>(x, Wd, b, outp, outi, cnt, list);
    } else {
        fallback_kernel<<<NROWS / 64, 64, 0, stream>>>(x, W, b, outp, outi);
    }
}